// Round 9
// baseline (235.692 us; speedup 1.0000x reference)
//
#include <hip/hip_runtime.h>
#include <math.h>
#include <stdint.h>

// ContentAttention fused, round 10: split-K (2 halves) + combine pass.
// R8 post-mortem: (1) total-kernel = ~103us FIXED harness overhead (single-
// kernel v9 proved it); convert_k+launch was only ~30us. (2) v3 (DMA B) and
// v8 (reg B) both = 64KB/kt/CU = ~85us -> per-CU inbound supply ~26 GB/s is
// the wall; only UNIQUE bytes/CU matter. v9's in-register split cost +33us
// -> keep convert_k.
// v10: each block = 128 q-rows x 256 keys (unique B 1 MB/block, halved),
// grid stays 256 (32 batch x 4 qchunk x 2 khalf) -> all CUs busy. 16 waves =
// 2 row-groups x 8 col-groups; wr-pair duplicate B loads dedup in L1 (drift
// bounded by per-body raw s_barrier). Partial softmax (guarded max/sum) to
// ws; combine kernel rescales the two halves + conf.
// Fallback v1 kept for ws_size < WS_TOTAL.

#define NB 32
#define NQ 512
#define NK 512
#define ND 1024
#define BK 32
#define NT (ND / BK)            // 32 k-tiles
#define BM1 64                  // fallback rows/block
#define BMP 128                 // attn_part rows/block
#define KHALF 256               // keys/block
#define AST2 264                // ushorts per A row (256-k quarter: 512B + 16B pad)
#define TILE_BYTES 65536        // per (batch,kt): 32KB hi + 32KB lo
#define WS_TILES ((size_t)NB * NT * TILE_BYTES)        // 64 MiB
#define MASK_BYTES ((size_t)NB * NK * 4)               // 64 KiB
#define MS_BYTES ((size_t)NB * NQ * 2 * 4)             // 128 KiB each (M,S)
#define WS_TOTAL (WS_TILES + MASK_BYTES + 2 * MS_BYTES)

typedef __attribute__((ext_vector_type(8))) short short8;
typedef __attribute__((ext_vector_type(4))) float f32x4;

__device__ __forceinline__ void bf_split(float x, unsigned& hbits, float& lo) {
  unsigned u = __float_as_uint(x);
  unsigned r = u + 0x7fffu + ((u >> 16) & 1u);
  hbits = r & 0xffff0000u;
  lo = x - __uint_as_float(hbits);
}
__device__ __forceinline__ unsigned pack_rn(float x0, float x1) {
  unsigned u0 = __float_as_uint(x0), u1 = __float_as_uint(x1);
  unsigned r0 = u0 + 0x7fffu + ((u0 >> 16) & 1u);
  unsigned r1 = u1 + 0x7fffu + ((u1 >> 16) & 1u);
  return (r0 >> 16) | (r1 & 0xffff0000u);
}

// Rotated LDS image (v1 fallback only).
__device__ __forceinline__ int lds_off_write(int r, int c4) {
  int slot = ((c4 >> 1) + (r >> 1)) & 3;
  return r * 32 + slot * 8 + (c4 & 1) * 4;
}
__device__ __forceinline__ int lds_off_read(int r, int quad) {
  int slot = (quad + (r >> 1)) & 3;
  return r * 32 + slot * 8;
}

// ---------------------------------------------------------------------------
// Kernel 1: K fp32 -> ws plain [col][k] bf16 hi/lo planes + mask floats
// ---------------------------------------------------------------------------
__global__ __launch_bounds__(256)
void convert_k(const float* __restrict__ Kg, unsigned char* __restrict__ ws) {
  const int bx = blockIdx.x;          // 0..1023
  const int batch = bx >> 5, kt = bx & 31;
  const float* src = Kg + (size_t)batch * NK * ND + kt * BK;
  unsigned short* hiB = (unsigned short*)(ws + (size_t)bx * TILE_BYTES);
  unsigned short* loB = hiB + 32768 / 2;
  float* maskB = (float*)(ws + WS_TILES) + batch * NK;

#pragma unroll
  for (int i = 0; i < 16; ++i) {
    int idx = threadIdx.x + 256 * i;
    int c = idx >> 3, c4 = idx & 7;
    float4 v = *(const float4*)(src + (size_t)c * ND + c4 * 4);
    unsigned h0, h1, h2, h3;
    float l0, l1, l2, l3;
    bf_split(v.x, h0, l0); bf_split(v.y, h1, l1);
    bf_split(v.z, h2, l2); bf_split(v.w, h3, l3);
    int off = c * 32 + c4 * 4;          // [col][k], 64B per col
    *(uint2*)(&hiB[off]) = make_uint2((h0 >> 16) | h1, (h2 >> 16) | h3);
    *(uint2*)(&loB[off]) = make_uint2(pack_rn(l0, l1), pack_rn(l2, l3));
    if (kt == 0 && c4 == 0) maskB[c] = v.x;
  }
}

#define MFMA_BF16 __builtin_amdgcn_mfma_f32_16x16x32_bf16

// One k-tile. CURB/NXTB: short8[4] register dbuf ([0]=hi nt0,[1]=hi nt1,
// [2]=lo nt0,[3]=lo nt1). Ends with a raw s_barrier (no waitcnt): bounds
// wr-pair drift to <=1 body so duplicate B loads hit L1. No data hazard —
// A-image is read-only within a quarter, B is per-wave registers.
#define BODYP(KT, CURB, NXTB)                                                  \
  do {                                                                         \
    if ((KT) + 1 < NT) {                                                       \
      const unsigned char* tb = wsB + (size_t)((KT) + 1) * TILE_BYTES;         \
      NXTB[0] = *(const short8*)(tb + boff);                                   \
      NXTB[1] = *(const short8*)(tb + 1024 + boff);                            \
      NXTB[2] = *(const short8*)(tb + 32768 + boff);                           \
      NXTB[3] = *(const short8*)(tb + 32768 + 1024 + boff);                    \
    }                                                                          \
    const int ktL = (KT) & 7;                                                  \
    short8 ahi[4], alo[4];                                                     \
    _Pragma("unroll") for (int mt = 0; mt < 4; ++mt) {                         \
      int off = (wr * 64 + mt * 16 + ln15) * AST2 + ktL * 32 + quad * 8;       \
      ahi[mt] = *(const short8*)(&sAhi[off]);                                  \
      alo[mt] = *(const short8*)(&sAlo[off]);                                  \
    }                                                                          \
    _Pragma("unroll") for (int nt = 0; nt < 2; ++nt) {                         \
      _Pragma("unroll") for (int mt = 0; mt < 4; ++mt) {                       \
        acc[mt][nt] = MFMA_BF16(ahi[mt], CURB[nt], acc[mt][nt], 0, 0, 0);      \
        acc[mt][nt] = MFMA_BF16(ahi[mt], CURB[2 + nt], acc[mt][nt], 0, 0, 0);  \
        acc[mt][nt] = MFMA_BF16(alo[mt], CURB[nt], acc[mt][nt], 0, 0, 0);      \
      }                                                                        \
    }                                                                          \
    __builtin_amdgcn_s_barrier();                                              \
  } while (0)

// ---------------------------------------------------------------------------
// Kernel 2: attn_part — 1024 thr, 16 waves = 2 row-groups x 8 col-groups,
// 128 q-rows x 256 keys per block, partial softmax out.
// ---------------------------------------------------------------------------
__global__ __launch_bounds__(1024, 4)
void attn_part(const float* __restrict__ Qg, const unsigned char* __restrict__ ws,
               float* __restrict__ attn, float* __restrict__ Mws,
               float* __restrict__ Sws) {
  __shared__ __align__(16) unsigned short sAhi[BMP * AST2];  // 66 KB
  __shared__ __align__(16) unsigned short sAlo[BMP * AST2];  // 66 KB
  __shared__ __align__(16) float sRed[BMP][8];               // 4 KB

  const int tid = threadIdx.x;
  const int g = blockIdx.x;                 // 0..255
  const int b = g & 31;                     // batch (co-XCD: XCD = b%8)
  const int qh = g >> 5;                    // 0..7
  const int qc = qh >> 1;                   // q-chunk of 128
  const int h = qh & 1;                     // key half
  const int ln = tid & 63, w = tid >> 6;
  const int ln15 = ln & 15, quad = ln >> 4;
  const int wr = w >> 3, wc = w & 7;        // row-group / col-group
  const int col0 = wc * 32;                 // within the 256-key half

  const float* Qp = Qg + ((size_t)b * NQ + qc * BMP) * ND;
  const unsigned char* wsB = ws + (size_t)b * NT * TILE_BYTES;
  const float* maskB = (const float*)(ws + WS_TILES) + b * NK;

  const int boff = ((h * KHALF + col0 + ln15) << 6) + (quad << 4);

  f32x4 acc[4][2];
#pragma unroll
  for (int mt = 0; mt < 4; ++mt)
#pragma unroll
    for (int nt = 0; nt < 2; ++nt) acc[mt][nt] = (f32x4){0.f, 0.f, 0.f, 0.f};

  // Stage one 256-k quarter of A (128 rows, hi/lo bf16, b128 writes).
  auto stage_quarter = [&](int kq) {
#pragma unroll
    for (int i = 0; i < 4; ++i) {
      int idx = tid + 1024 * i;             // 4096 units = 128 rows x 32 chunks
      int row = idx >> 5, kc8 = idx & 31;
      const float* p = Qp + (size_t)row * ND + kq * 256 + kc8 * 8;
      float4 va = *(const float4*)(p);
      float4 vb = *(const float4*)(p + 4);
      unsigned h0, h1, h2, h3, h4, h5, h6, h7;
      float l0, l1, l2, l3, l4, l5, l6, l7;
      bf_split(va.x, h0, l0); bf_split(va.y, h1, l1);
      bf_split(va.z, h2, l2); bf_split(va.w, h3, l3);
      bf_split(vb.x, h4, l4); bf_split(vb.y, h5, l5);
      bf_split(vb.z, h6, l6); bf_split(vb.w, h7, l7);
      int off = row * AST2 + kc8 * 8;
      *(uint4*)(&sAhi[off]) = make_uint4((h0 >> 16) | h1, (h2 >> 16) | h3,
                                         (h4 >> 16) | h5, (h6 >> 16) | h7);
      *(uint4*)(&sAlo[off]) = make_uint4(pack_rn(l0, l1), pack_rn(l2, l3),
                                         pack_rn(l4, l5), pack_rn(l6, l7));
    }
  };

  // ---- prologue ----
  stage_quarter(0);
  short8 pbA[4], pbB[4];
  pbA[0] = *(const short8*)(wsB + boff);
  pbA[1] = *(const short8*)(wsB + 1024 + boff);
  pbA[2] = *(const short8*)(wsB + 32768 + boff);
  pbA[3] = *(const short8*)(wsB + 32768 + 1024 + boff);
  __syncthreads();

  // ---- 4 quarters x 8 bodies ----
#pragma unroll 1
  for (int kq = 0; kq < 4; ++kq) {
    if (kq) {
      __syncthreads();            // all frag reads of previous quarter done
      stage_quarter(kq);
      __syncthreads();            // image ready
    }
    const int k0 = kq * 8;
    BODYP(k0 + 0, pbA, pbB);
    BODYP(k0 + 1, pbB, pbA);
    BODYP(k0 + 2, pbA, pbB);
    BODYP(k0 + 3, pbB, pbA);
    BODYP(k0 + 4, pbA, pbB);
    BODYP(k0 + 5, pbB, pbA);
    BODYP(k0 + 6, pbA, pbB);
    BODYP(k0 + 7, pbB, pbA);
  }

  // ======= epilogue: mask + PARTIAL softmax (this key-half only) =======
  const float NEGINF = -__builtin_inff();
  float rm[4][4];
#pragma unroll
  for (int mt = 0; mt < 4; ++mt)
#pragma unroll
    for (int rg = 0; rg < 4; ++rg) rm[mt][rg] = NEGINF;

#pragma unroll
  for (int nt = 0; nt < 2; ++nt) {
    int col = h * KHALF + col0 + nt * 16 + ln15;
    bool msk = (maskB[col] == 0.0f);
#pragma unroll
    for (int mt = 0; mt < 4; ++mt)
#pragma unroll
      for (int rg = 0; rg < 4; ++rg) {
        float v = msk ? NEGINF : acc[mt][nt][rg];
        acc[mt][nt][rg] = v;
        rm[mt][rg] = fmaxf(rm[mt][rg], v);
      }
  }
#pragma unroll
  for (int mt = 0; mt < 4; ++mt)
#pragma unroll
    for (int rg = 0; rg < 4; ++rg) {
      float v = rm[mt][rg];
#pragma unroll
      for (int d = 1; d < 16; d <<= 1) v = fmaxf(v, __shfl_xor(v, d, 64));
      rm[mt][rg] = v;
    }
  if (ln15 == 0) {
#pragma unroll
    for (int mt = 0; mt < 4; ++mt)
#pragma unroll
      for (int rg = 0; rg < 4; ++rg)
        sRed[wr * 64 + mt * 16 + quad * 4 + rg][wc] = rm[mt][rg];
  }
  __syncthreads();

  float gmax[4][4], gsum[4][4];
#pragma unroll
  for (int mt = 0; mt < 4; ++mt)
#pragma unroll
    for (int rg = 0; rg < 4; ++rg) {
      int row = wr * 64 + mt * 16 + quad * 4 + rg;
      f32x4 p0 = *(const f32x4*)(&sRed[row][0]);
      f32x4 p1 = *(const f32x4*)(&sRed[row][4]);
      gmax[mt][rg] = fmaxf(fmaxf(fmaxf(p0[0], p0[1]), fmaxf(p0[2], p0[3])),
                           fmaxf(fmaxf(p1[0], p1[1]), fmaxf(p1[2], p1[3])));
      gsum[mt][rg] = 0.f;
    }

#pragma unroll
  for (int nt = 0; nt < 2; ++nt)
#pragma unroll
    for (int mt = 0; mt < 4; ++mt)
#pragma unroll
      for (int rg = 0; rg < 4; ++rg) {
        // all-masked guard: m=-inf -> use 0 so exp(-inf)=0 (not NaN)
        float mu = (gmax[mt][rg] == NEGINF) ? 0.f : gmax[mt][rg];
        float e = __expf(acc[mt][nt][rg] - mu);
        acc[mt][nt][rg] = e;
        gsum[mt][rg] += e;
      }
#pragma unroll
  for (int mt = 0; mt < 4; ++mt)
#pragma unroll
    for (int rg = 0; rg < 4; ++rg) {
      float v = gsum[mt][rg];
#pragma unroll
      for (int d = 1; d < 16; d <<= 1) v += __shfl_xor(v, d, 64);
      gsum[mt][rg] = v;
    }
  __syncthreads();              // sRed(max) reads done — safe to overwrite
  if (ln15 == 0) {
#pragma unroll
    for (int mt = 0; mt < 4; ++mt)
#pragma unroll
      for (int rg = 0; rg < 4; ++rg)
        sRed[wr * 64 + mt * 16 + quad * 4 + rg][wc] = gsum[mt][rg];
  }
  __syncthreads();
#pragma unroll
  for (int mt = 0; mt < 4; ++mt)
#pragma unroll
    for (int rg = 0; rg < 4; ++rg) {
      int row = wr * 64 + mt * 16 + quad * 4 + rg;
      f32x4 p0 = *(const f32x4*)(&sRed[row][0]);
      f32x4 p1 = *(const f32x4*)(&sRed[row][4]);
      gsum[mt][rg] = ((p0[0] + p0[1]) + (p0[2] + p0[3])) +
                     ((p1[0] + p1[1]) + (p1[2] + p1[3]));
    }

  // write unnormalized P into final attn location (this half's columns)
  float* outBase = attn + ((size_t)b * NQ + qc * BMP) * NK + h * KHALF;
#pragma unroll
  for (int mt = 0; mt < 4; ++mt)
#pragma unroll
    for (int rg = 0; rg < 4; ++rg) {
      int row = wr * 64 + mt * 16 + quad * 4 + rg;
#pragma unroll
      for (int nt = 0; nt < 2; ++nt)
        outBase[(size_t)row * NK + col0 + nt * 16 + ln15] = acc[mt][nt][rg];
    }

  // write partial m,s (one rep per row: wc==0, ln15==0 -> waves 0 and 8)
  if (wc == 0 && ln15 == 0) {
#pragma unroll
    for (int mt = 0; mt < 4; ++mt)
#pragma unroll
      for (int rg = 0; rg < 4; ++rg) {
        int row = wr * 64 + mt * 16 + quad * 4 + rg;
        size_t R = (size_t)b * NQ + qc * BMP + row;
        Mws[R * 2 + h] = gmax[mt][rg];
        Sws[R * 2 + h] = gsum[mt][rg];
      }
  }
}

// ---------------------------------------------------------------------------
// Kernel 3: combine — per q-row, merge 2 half-softmaxes, rescale, conf.
// ---------------------------------------------------------------------------
__global__ __launch_bounds__(256)
void combine(float* __restrict__ attn, const float* __restrict__ Mws,
             const float* __restrict__ Sws, const float* __restrict__ Tp,
             const float* __restrict__ Bp, float* __restrict__ conf) {
  const int tid = threadIdx.x;
  const int ln = tid & 63;
  const size_t R = (size_t)blockIdx.x * 4 + (tid >> 6);   // global q-row

  float m0 = Mws[R * 2], m1 = Mws[R * 2 + 1];
  float s0 = Sws[R * 2], s1 = Sws[R * 2 + 1];
  const float NEGINF = -__builtin_inff();
  float M = fmaxf(m0, m1);
  float sc0 = 0.f, sc1 = 0.f, lse = NEGINF;
  if (M > NEGINF) {
    float f0 = __expf(m0 - M);              // m=-inf -> 0
    float f1 = __expf(m1 - M);
    float S = s0 * f0 + s1 * f1;
    float inv = (S > 0.f) ? 1.0f / S : 0.f;
    sc0 = f0 * inv;
    sc1 = f1 * inv;
    lse = M + __logf(S);
  }

  float* row = attn + R * NK;
  float sc = (ln < 32) ? sc0 : sc1;         // lanes 0-31: cols 0-255
  f32x4 v0 = *(const f32x4*)(row + ln * 8);
  f32x4 v1 = *(const f32x4*)(row + ln * 8 + 4);
  v0 *= sc;
  v1 *= sc;
  *(f32x4*)(row + ln * 8) = v0;
  *(f32x4*)(row + ln * 8 + 4) = v1;

  if (ln == 0) {
    float t = (lse + Bp[0]) * Tp[0];
    conf[R] = 1.0f / (1.0f + __expf(-t));
  }
}

// ---------------------------------------------------------------------------
// Fallback: R1 single-kernel path (used only if ws_size < WS_TOTAL)
// ---------------------------------------------------------------------------
__global__ __launch_bounds__(256, 1)
void attn_fused_v1(const float* __restrict__ Qg, const float* __restrict__ Kg,
                   const float* __restrict__ Tp, const float* __restrict__ Bp,
                   float* __restrict__ attn, float* __restrict__ conf) {
  __shared__ __align__(16) unsigned short sAhi[BM1 * BK];
  __shared__ __align__(16) unsigned short sAlo[BM1 * BK];
  __shared__ __align__(16) unsigned short sBhi[NK * BK];
  __shared__ __align__(16) unsigned short sBlo[NK * BK];
  __shared__ float sRedA[4][BM1];
  __shared__ float sRedB[4][BM1];

  const int tid = threadIdx.x;
  const int g = blockIdx.x;
  const int batch = g & 31;
  const int q0 = (g >> 5) * BM1;
  const int ln = tid & 63, w = tid >> 6;
  const int ln15 = ln & 15, quad = ln >> 4;
  const int wn0 = w * 128;

  const float* Qp = Qg + ((size_t)batch * NQ + q0) * ND;
  const float* Kp = Kg + (size_t)batch * NK * ND;

  f32x4 acc[4][8];
#pragma unroll
  for (int mt = 0; mt < 4; ++mt)
#pragma unroll
    for (int nt = 0; nt < 8; ++nt) acc[mt][nt] = (f32x4){0.f, 0.f, 0.f, 0.f};

  float4 pb[16], pa[2];
#pragma unroll
  for (int i = 0; i < 16; ++i) {
    int idx = tid + 256 * i, r = idx >> 3, c4 = idx & 7;
    pb[i] = *(const float4*)(Kp + (size_t)r * ND + c4 * 4);
  }
#pragma unroll
  for (int i = 0; i < 2; ++i) {
    int idx = tid + 256 * i, r = idx >> 3, c4 = idx & 7;
    pa[i] = *(const float4*)(Qp + (size_t)r * ND + c4 * 4);
  }

  for (int kt = 0; kt < NT; ++kt) {
    if (kt) __syncthreads();
#pragma unroll
    for (int i = 0; i < 2; ++i) {
      int idx = tid + 256 * i, r = idx >> 3, c4 = idx & 7;
      int off = lds_off_write(r, c4);
      unsigned h0, h1, h2, h3; float l0, l1, l2, l3;
      bf_split(pa[i].x, h0, l0); bf_split(pa[i].y, h1, l1);
      bf_split(pa[i].z, h2, l2); bf_split(pa[i].w, h3, l3);
      *(uint2*)(&sAhi[off]) = make_uint2((h0 >> 16) | h1, (h2 >> 16) | h3);
      *(uint2*)(&sAlo[off]) = make_uint2(pack_rn(l0, l1), pack_rn(l2, l3));
    }
#pragma unroll
    for (int i = 0; i < 16; ++i) {
      int idx = tid + 256 * i, r = idx >> 3, c4 = idx & 7;
      int off = lds_off_write(r, c4);
      unsigned h0, h1, h2, h3; float l0, l1, l2, l3;
      bf_split(pb[i].x, h0, l0); bf_split(pb[i].y, h1, l1);
      bf_split(pb[i].z, h2, l2); bf_split(pb[i].w, h3, l3);
      *(uint2*)(&sBhi[off]) = make_uint2((h0 >> 16) | h1, (h2 >> 16) | h3);
      *(uint2*)(&sBlo[off]) = make_uint2(pack_rn(l0, l1), pack_rn(l2, l3));
    }
    __syncthreads();

    if (kt < NT - 1) {
      const float* Kq = Kp + (kt + 1) * BK;
      const float* Qq = Qp + (kt + 1) * BK;
#pragma unroll
      for (int i = 0; i < 16; ++i) {
        int idx = tid + 256 * i, r = idx >> 3, c4 = idx & 7;
        pb[i] = *(const float4*)(Kq + (size_t)r * ND + c4 * 4);
      }
#pragma unroll
      for (int i = 0; i < 2; ++i) {
        int idx = tid + 256 * i, r = idx >> 3, c4 = idx & 7;
        pa[i] = *(const float4*)(Qq + (size_t)r * ND + c4 * 4);
      }
    }

    short8 ahi[4], alo[4];
#pragma unroll
    for (int mt = 0; mt < 4; ++mt) {
      int off = lds_off_read(mt * 16 + ln15, quad);
      ahi[mt] = *(const short8*)(&sAhi[off]);
      alo[mt] = *(const short8*)(&sAlo[off]);
    }
#pragma unroll
    for (int nt = 0; nt < 8; ++nt) {
      int off = lds_off_read(wn0 + nt * 16 + ln15, quad);
      short8 bhi = *(const short8*)(&sBhi[off]);
      short8 blo = *(const short8*)(&sBlo[off]);
#pragma unroll
      for (int mt = 0; mt < 4; ++mt) {
        acc[mt][nt] = MFMA_BF16(ahi[mt], bhi, acc[mt][nt], 0, 0, 0);
        acc[mt][nt] = MFMA_BF16(ahi[mt], blo, acc[mt][nt], 0, 0, 0);
        acc[mt][nt] = MFMA_BF16(alo[mt], bhi, acc[mt][nt], 0, 0, 0);
      }
    }
  }

  const float NEGINF = -__builtin_inff();
  float rm[4][4];
#pragma unroll
  for (int mt = 0; mt < 4; ++mt)
#pragma unroll
    for (int rg = 0; rg < 4; ++rg) rm[mt][rg] = NEGINF;
#pragma unroll
  for (int nt = 0; nt < 8; ++nt) {
    int col = wn0 + nt * 16 + ln15;
    bool msk = (Kp[(size_t)col * ND] == 0.0f);
#pragma unroll
    for (int mt = 0; mt < 4; ++mt)
#pragma unroll
      for (int rg = 0; rg < 4; ++rg) {
        float v = msk ? NEGINF : acc[mt][nt][rg];
        acc[mt][nt][rg] = v;
        rm[mt][rg] = fmaxf(rm[mt][rg], v);
      }
  }
#pragma unroll
  for (int mt = 0; mt < 4; ++mt)
#pragma unroll
    for (int rg = 0; rg < 4; ++rg) {
      float v = rm[mt][rg];
#pragma unroll
      for (int d = 1; d < 16; d <<= 1) v = fmaxf(v, __shfl_xor(v, d, 64));
      rm[mt][rg] = v;
    }
  if (ln15 == 0)
#pragma unroll
    for (int mt = 0; mt < 4; ++mt)
#pragma unroll
      for (int rg = 0; rg < 4; ++rg)
        sRedA[w][mt * 16 + quad * 4 + rg] = rm[mt][rg];
  __syncthreads();

  float gmax[4][4], gsum[4][4];
#pragma unroll
  for (int mt = 0; mt < 4; ++mt)
#pragma unroll
    for (int rg = 0; rg < 4; ++rg) {
      int row = mt * 16 + quad * 4 + rg;
      gmax[mt][rg] = fmaxf(fmaxf(sRedA[0][row], sRedA[1][row]),
                           fmaxf(sRedA[2][row], sRedA[3][row]));
      gsum[mt][rg] = 0.f;
    }
#pragma unroll
  for (int nt = 0; nt < 8; ++nt)
#pragma unroll
    for (int mt = 0; mt < 4; ++mt)
#pragma unroll
      for (int rg = 0; rg < 4; ++rg) {
        float e = __expf(acc[mt][nt][rg] - gmax[mt][rg]);
        acc[mt][nt][rg] = e;
        gsum[mt][rg] += e;
      }
#pragma unroll
  for (int mt = 0; mt < 4; ++mt)
#pragma unroll
    for (int rg = 0; rg < 4; ++rg) {
      float v = gsum[mt][rg];
#pragma unroll
      for (int d = 1; d < 16; d <<= 1) v += __shfl_xor(v, d, 64);
      gsum[mt][rg] = v;
    }
  if (ln15 == 0)
#pragma unroll
    for (int mt = 0; mt < 4; ++mt)
#pragma unroll
      for (int rg = 0; rg < 4; ++rg)
        sRedB[w][mt * 16 + quad * 4 + rg] = gsum[mt][rg];
  __syncthreads();
#pragma unroll
  for (int mt = 0; mt < 4; ++mt)
#pragma unroll
    for (int rg = 0; rg < 4; ++rg) {
      int row = mt * 16 + quad * 4 + rg;
      gsum[mt][rg] = sRedB[0][row] + sRedB[1][row] + sRedB[2][row] + sRedB[3][row];
    }

  float* outBase = attn + ((size_t)batch * NQ + q0) * NK;
#pragma unroll
  for (int mt = 0; mt < 4; ++mt)
#pragma unroll
    for (int rg = 0; rg < 4; ++rg) {
      int row = mt * 16 + quad * 4 + rg;
      float inv = 1.0f / gsum[mt][rg];
#pragma unroll
      for (int nt = 0; nt < 8; ++nt)
        outBase[(size_t)row * NK + wn0 + nt * 16 + ln15] = acc[mt][nt][rg] * inv;
    }
  if (w == 0 && ln15 == 0) {
    float tv = Tp[0], bv = Bp[0];
#pragma unroll
    for (int mt = 0; mt < 4; ++mt)
#pragma unroll
      for (int rg = 0; rg < 4; ++rg) {
        int row = mt * 16 + quad * 4 + rg;
        float lse = gmax[mt][rg] + __logf(gsum[mt][rg]);
        float t = (lse + bv) * tv;
        conf[(size_t)batch * NQ + q0 + row] = 1.0f / (1.0f + __expf(-t));
      }
  }
}

extern "C" void kernel_launch(void* const* d_in, const int* in_sizes, int n_in,
                              void* d_out, int out_size, void* d_ws, size_t ws_size,
                              hipStream_t stream) {
  const float* q = (const float*)d_in[0];
  const float* k = (const float*)d_in[1];
  const float* temp = (const float*)d_in[2];
  const float* bias = (const float*)d_in[3];
  float* attn = (float*)d_out;
  float* conf = attn + (size_t)NB * NQ * NK;

  if (ws_size >= WS_TOTAL) {
    unsigned char* ws = (unsigned char*)d_ws;
    float* Mws = (float*)(ws + WS_TILES + MASK_BYTES);
    float* Sws = (float*)(ws + WS_TILES + MASK_BYTES + MS_BYTES);
    hipLaunchKernelGGL(convert_k, dim3(NB * NT), dim3(256), 0, stream,
                       k, ws);
    hipLaunchKernelGGL(attn_part, dim3(NB * (NQ / BMP) * 2), dim3(1024), 0,
                       stream, q, ws, attn, Mws, Sws);
    hipLaunchKernelGGL(combine, dim3(NB * NQ / 4), dim3(256), 0, stream,
                       attn, Mws, Sws, temp, bias, conf);
  } else {
    hipLaunchKernelGGL(attn_fused_v1, dim3(NB * (NQ / BM1)), dim3(256), 0, stream,
                       q, k, temp, bias, attn, conf);
  }
}